// Round 6
// baseline (355.079 us; speedup 1.0000x reference)
//
#include <hip/hip_runtime.h>
#include <hip/hip_bf16.h>

#define H 256
#define NSC 512
#define MQ 4096
#define BATCH 4

typedef __attribute__((ext_vector_type(8))) short bf16x8;
typedef __attribute__((ext_vector_type(4))) float f32x4;

__device__ __forceinline__ ushort f2bf(float x) {
    union { float f; unsigned u; } c; c.f = x;
    unsigned r = c.u + 0x7FFF + ((c.u >> 16) & 1);   // RNE
    return (ushort)(r >> 16);
}
// pack bf16(hi),bf16(lo) -> one dword (truncation, 1 v_perm)
__device__ __forceinline__ unsigned pk2(float hi, float lo) {
    union { float f; unsigned u; } a, b; a.f = hi; b.f = lo;
    return __builtin_amdgcn_perm(a.u, b.u, 0x07060302u);
}
__device__ __forceinline__ uint4 cvt8f(const float* p) {
    float4 a = *(const float4*)p;
    float4 b = *(const float4*)(p + 4);
    uint4 r;
    r.x = pk2(a.y, a.x); r.y = pk2(a.w, a.z);
    r.z = pk2(b.y, b.x); r.w = pk2(b.w, b.z);
    return r;
}
#define EXP2(x) __builtin_amdgcn_exp2f(x)

// ---- weights f32 -> bf16, 4 tensors ----
struct Cvt4 { const float* s[4]; ushort* d[4]; int n[4]; };
__global__ __launch_bounds__(256) void cvt_kernel(Cvt4 a) {
    const int sl = blockIdx.y;
    const int i = (blockIdx.x * 256 + threadIdx.x) * 8;
    if (i >= a.n[sl]) return;
    *(uint4*)(a.d[sl] + i) = cvt8f(a.s[sl] + i);
}

// ---- bf16 MFMA GEMM, block = 32 rows x NC cols, 512 thr.
// NC=256: 8 waves 1x8 (each: 32 rows, 32 cols). NC=128: 8 waves 2x4.
// A: f32 (ATYPE 0, inline cvt) or bf16 (ATYPE 1). W: bf16 (preconverted).
// MODE 0: out = bf16(act((A@W^T + bias)*alpha)), stride N.
// MODE 1: kv split: col<256 -> bf16 k[row*256+col]; col>=256 -> vT
//         out2[((row>>9)*256 + col-256)*512 + (row&511)].
// MODE 2: fused add+LN over 256-col rows: f32 out + optional bf16 out2.
template<int ATYPE, int MODE, int NC>
__global__ __launch_bounds__(512, 6) void gemm_kernel(
    const void* __restrict__ Ain, const ushort* __restrict__ Wb,
    const float* __restrict__ bias, const float* __restrict__ res,
    const float* __restrict__ lng, const float* __restrict__ lnb,
    void* __restrict__ out, ushort* __restrict__ out2,
    int K, int N, float alpha, int relu)
{
    __shared__ ushort As[32 * 64];
    __shared__ ushort Bs[NC * 64];
    __shared__ float Ls[32 * 8];
    __shared__ float Lq[32 * 8];
    const int t = threadIdx.x;
    const int w = t >> 6, lane = t & 63, g = lane >> 4, l15 = lane & 15;
    const int rowBase = blockIdx.y * 32, colBase = blockIdx.x * NC;
    constexpr int MT = (NC == 256) ? 2 : 1;
    constexpr int BI = NC / 64;
    const int wrB = (NC == 256) ? 0 : ((w >> 2) * 16);
    const int wcB = (NC == 256) ? (w * 32) : ((w & 3) * 32);
    f32x4 acc[MT][2];
    #pragma unroll
    for (int mt = 0; mt < MT; mt++) {
        acc[mt][0] = (f32x4){0.f,0.f,0.f,0.f};
        acc[mt][1] = (f32x4){0.f,0.f,0.f,0.f};
    }
    const int ar = t >> 3, akc = t & 7, ap = akc ^ (ar & 7);

    for (int k0 = 0; k0 < K; k0 += 64) {
        uint4 av;
        if (t < 256) {
            if constexpr (ATYPE == 0)
                av = cvt8f((const float*)Ain + (size_t)(rowBase + ar) * K + k0 + akc*8);
            else
                av = *(const uint4*)((const ushort*)Ain + (size_t)(rowBase + ar) * K + k0 + akc*8);
        }
        uint4 bv[BI];
        #pragma unroll
        for (int i = 0; i < BI; i++) {
            const int u = t + 512*i, br = u >> 3, bkc = u & 7;
            bv[i] = *(const uint4*)(Wb + (size_t)(colBase + br) * K + k0 + bkc*8);
        }
        __syncthreads();
        if (t < 256) *(uint4*)&As[ar*64 + ap*8] = av;
        #pragma unroll
        for (int i = 0; i < BI; i++) {
            const int u = t + 512*i, br = u >> 3, bkc = u & 7, bp = bkc ^ (br & 7);
            *(uint4*)&Bs[br*64 + bp*8] = bv[i];
        }
        __syncthreads();
        #pragma unroll
        for (int kk = 0; kk < 2; kk++) {
            const int swz = ((kk*4 + g) ^ (l15 & 7)) * 8;
            bf16x8 af[MT], bfr[2];
            #pragma unroll
            for (int mt = 0; mt < MT; mt++)
                af[mt] = *(const bf16x8*)&As[(wrB + mt*16 + l15)*64 + swz];
            #pragma unroll
            for (int nt = 0; nt < 2; nt++)
                bfr[nt] = *(const bf16x8*)&Bs[(wcB + nt*16 + l15)*64 + swz];
            #pragma unroll
            for (int mt = 0; mt < MT; mt++)
                #pragma unroll
                for (int nt = 0; nt < 2; nt++)
                    acc[mt][nt] = __builtin_amdgcn_mfma_f32_16x16x32_bf16(
                        af[mt], bfr[nt], acc[mt][nt], 0, 0, 0);
        }
    }

    if constexpr (MODE == 0) {
        #pragma unroll
        for (int nt = 0; nt < 2; nt++) {
            const int col = colBase + wcB + nt*16 + l15;
            const float bb = bias[col];
            #pragma unroll
            for (int mt = 0; mt < MT; mt++)
                #pragma unroll
                for (int r = 0; r < 4; r++) {
                    const int row = rowBase + wrB + mt*16 + g*4 + r;
                    float o = (acc[mt][nt][r] + bb) * alpha;
                    if (relu) o = fmaxf(o, 0.f);
                    ((ushort*)out)[(size_t)row * N + col] = f2bf(o);
                }
        }
    } else if constexpr (MODE == 1) {
        #pragma unroll
        for (int nt = 0; nt < 2; nt++) {
            const int col = colBase + wcB + nt*16 + l15;
            const float bb = bias[col];
            #pragma unroll
            for (int mt = 0; mt < MT; mt++) {
                const int row0 = rowBase + mt*16 + g*4;
                if (col < 256) {
                    #pragma unroll
                    for (int r = 0; r < 4; r++)
                        ((ushort*)out)[(size_t)(row0 + r) * 256 + col] = f2bf(acc[mt][nt][r] + bb);
                } else {
                    ushort4 pkv = { f2bf(acc[mt][nt][0] + bb), f2bf(acc[mt][nt][1] + bb),
                                    f2bf(acc[mt][nt][2] + bb), f2bf(acc[mt][nt][3] + bb) };
                    *(ushort4*)&out2[(size_t)((row0 >> 9)*256 + col - 256) * 512 + (row0 & 511)] = pkv;
                }
            }
        }
    } else {
        float bb[2], gv[2], btv[2];
        #pragma unroll
        for (int nt = 0; nt < 2; nt++) {
            const int col = wcB + nt*16 + l15;
            bb[nt] = bias[col]; gv[nt] = lng[col]; btv[nt] = lnb[col];
        }
        #pragma unroll
        for (int mt = 0; mt < 2; mt++)
            #pragma unroll
            for (int r = 0; r < 4; r++) {
                const int row = rowBase + mt*16 + g*4 + r;
                const float* rp = res + (size_t)row * 256 + wcB;
                #pragma unroll
                for (int nt = 0; nt < 2; nt++)
                    acc[mt][nt][r] += bb[nt] + rp[nt*16 + l15];
            }
        #pragma unroll
        for (int mt = 0; mt < 2; mt++)
            #pragma unroll
            for (int r = 0; r < 4; r++) {
                float s = acc[mt][0][r] + acc[mt][1][r];
                float qq = acc[mt][0][r]*acc[mt][0][r] + acc[mt][1][r]*acc[mt][1][r];
                #pragma unroll
                for (int m = 1; m < 16; m <<= 1) {
                    s += __shfl_xor(s, m);
                    qq += __shfl_xor(qq, m);
                }
                if (l15 == 0) {
                    const int ri = mt*16 + g*4 + r;
                    Ls[ri*8 + w] = s;
                    Lq[ri*8 + w] = qq;
                }
            }
        __syncthreads();
        #pragma unroll
        for (int mt = 0; mt < 2; mt++)
            #pragma unroll
            for (int r = 0; r < 4; r++) {
                const int ri = mt*16 + g*4 + r;
                const int row = rowBase + ri;
                f32x4 s0 = *(const f32x4*)&Ls[ri*8];
                f32x4 s1 = *(const f32x4*)&Ls[ri*8 + 4];
                f32x4 q0 = *(const f32x4*)&Lq[ri*8];
                f32x4 q1 = *(const f32x4*)&Lq[ri*8 + 4];
                const float mu = ((s0[0]+s0[1])+(s0[2]+s0[3])+(s1[0]+s1[1])+(s1[2]+s1[3])) * (1.f/256.f);
                const float ex2 = ((q0[0]+q0[1])+(q0[2]+q0[3])+(q1[0]+q1[1])+(q1[2]+q1[3])) * (1.f/256.f);
                const float rs = rsqrtf(ex2 - mu*mu + 1e-6f);
                #pragma unroll
                for (int nt = 0; nt < 2; nt++) {
                    const int col = wcB + nt*16 + l15;
                    const float o = (acc[mt][nt][r] - mu) * rs * gv[nt] + btv[nt];
                    ((float*)out)[(size_t)row * 256 + col] = o;
                    if (out2) out2[(size_t)row * 256 + col] = f2bf(o);
                }
            }
    }
}

// ---- Flash MFMA cross-attention, S^T + in-register P transpose (no LDS
// roundtrip). Block = 512 thr = 8 waves (wave = head), 16 queries, grid 1024.
// QK: mfma(A=K,B=Q) -> lane(g,l15) holds S^T[key=kt*16+g*4+r][q=l15].
// Transpose to PV A-frag (P[q=l15][key=g*8..+7]) = 8 __shfl + 4 cndmask.
// K/V register-prefetched one chunk ahead (L2-hot). q pre-scaled by
// log2(e)/sqrt(d) so p = exp2(s). One barrier total.
__global__ __launch_bounds__(512, 8) void attn_kernel(
    const ushort* __restrict__ q, const ushort* __restrict__ k,
    const ushort* __restrict__ vt, ushort* __restrict__ ctx_out,
    float* __restrict__ attn_score)
{
    __shared__ float Lg[128];
    const int t = threadIdx.x;
    const int w = t >> 6, lane = t & 63, g = lane >> 4, l15 = lane & 15;
    const int b = blockIdx.x >> 8;
    const int m0 = (blockIdx.x & 255) * 16;

    const size_t qrow = (size_t)(b*MQ + m0 + l15) * H;
    const size_t kg = (size_t)b * NSC * H;
    const size_t vg = (size_t)b * H * NSC;

    const bf16x8 qf = *(const bf16x8*)&q[qrow + w*32 + g*8];
    const ushort* kp = k + kg + (size_t)l15 * H + w*32 + g*8;      // + key*H
    const ushort* vp = vt + vg + (size_t)(w*32 + l15) * NSC + g*8; // + dt*16*NSC + key

    const int srcA = ((2*g) & 3)*16 + l15;
    const int srcB = ((2*g + 1) & 3)*16 + l15;
    const bool hi = g >= 2;

    f32x4 c0 = (f32x4){0.f,0.f,0.f,0.f};
    f32x4 c1 = (f32x4){0.f,0.f,0.f,0.f};
    float lacc = 0.f;

    bf16x8 nk0 = *(const bf16x8*)(kp);
    bf16x8 nk1 = *(const bf16x8*)(kp + (size_t)16*H);
    bf16x8 nv0 = *(const bf16x8*)(vp);
    bf16x8 nv1 = *(const bf16x8*)(vp + 16*NSC);

    #pragma unroll 4
    for (int c = 0; c < 16; c++) {
        bf16x8 k0f = nk0, k1f = nk1, v0f = nv0, v1f = nv1;
        const int cn = ((c + 1) & 15) * 32;
        nk0 = *(const bf16x8*)(kp + (size_t)cn * H);
        nk1 = *(const bf16x8*)(kp + (size_t)(cn + 16) * H);
        nv0 = *(const bf16x8*)(vp + cn);
        nv1 = *(const bf16x8*)(vp + 16*NSC + cn);

        f32x4 s0 = __builtin_amdgcn_mfma_f32_16x16x32_bf16(k0f, qf, (f32x4){0.f,0.f,0.f,0.f}, 0, 0, 0);
        f32x4 s1 = __builtin_amdgcn_mfma_f32_16x16x32_bf16(k1f, qf, (f32x4){0.f,0.f,0.f,0.f}, 0, 0, 0);
        float e00 = EXP2(s0[0]), e01 = EXP2(s0[1]), e02 = EXP2(s0[2]), e03 = EXP2(s0[3]);
        float e10 = EXP2(s1[0]), e11 = EXP2(s1[1]), e12 = EXP2(s1[2]), e13 = EXP2(s1[3]);
        lacc += ((e00 + e01) + (e02 + e03)) + ((e10 + e11) + (e12 + e13));
        const unsigned p0x = pk2(e01, e00), p0y = pk2(e03, e02);
        const unsigned p1x = pk2(e11, e10), p1y = pk2(e13, e12);

        const unsigned a0 = (unsigned)__shfl((int)p0x, srcA);
        const unsigned b0 = (unsigned)__shfl((int)p1x, srcA);
        const unsigned a1 = (unsigned)__shfl((int)p0y, srcA);
        const unsigned b1 = (unsigned)__shfl((int)p1y, srcA);
        const unsigned a2 = (unsigned)__shfl((int)p0x, srcB);
        const unsigned b2 = (unsigned)__shfl((int)p1x, srcB);
        const unsigned a3 = (unsigned)__shfl((int)p0y, srcB);
        const unsigned b3 = (unsigned)__shfl((int)p1y, srcB);
        union { uint4 u; bf16x8 v; } pu;
        pu.u.x = hi ? b0 : a0;
        pu.u.y = hi ? b1 : a1;
        pu.u.z = hi ? b2 : a2;
        pu.u.w = hi ? b3 : a3;

        c0 = __builtin_amdgcn_mfma_f32_16x16x32_bf16(pu.v, v0f, c0, 0, 0, 0);
        c1 = __builtin_amdgcn_mfma_f32_16x16x32_bf16(pu.v, v1f, c1, 0, 0, 0);
    }

    float lsum = lacc;
    lsum += __shfl_xor(lsum, 16);
    lsum += __shfl_xor(lsum, 32);
    const float invl = 1.f / lsum;

    float ir[4];
    #pragma unroll
    for (int r = 0; r < 4; r++) ir[r] = __shfl(invl, g*4 + r);
    #pragma unroll
    for (int r = 0; r < 4; r++) {
        const size_t orow = (size_t)(b*MQ + m0 + g*4 + r) * H + w*32 + l15;
        ctx_out[orow]      = f2bf(c0[r] * ir[r]);
        ctx_out[orow + 16] = f2bf(c1[r] * ir[r]);
    }

    if (lane < 16) Lg[w*16 + lane] = -__log2f(lsum) - 3.0f;  // folds 1/l, 1/8
    __syncthreads();

    // ---- pass 2: score = mean over heads; wave covers chunks w, w+8 ----
    float lgl[8];
    #pragma unroll
    for (int h = 0; h < 8; h++) lgl[h] = Lg[h*16 + l15];

    #pragma unroll
    for (int cc = 0; cc < 2; cc++) {
        const int kbase = (w + cc*8) * 32;
        const ushort* kp2 = k + kg + (size_t)(kbase + l15) * H + g*8;
        f32x4 a0 = (f32x4){0.f,0.f,0.f,0.f};
        f32x4 a1 = (f32x4){0.f,0.f,0.f,0.f};
        #pragma unroll
        for (int h = 0; h < 8; h++) {
            bf16x8 qh = *(const bf16x8*)&q[qrow + h*32 + g*8];
            bf16x8 ka = *(const bf16x8*)(kp2 + h*32);
            bf16x8 kb2 = *(const bf16x8*)(kp2 + (size_t)16*H + h*32);
            f32x4 s = __builtin_amdgcn_mfma_f32_16x16x32_bf16(ka, qh, (f32x4){0.f,0.f,0.f,0.f}, 0, 0, 0);
            #pragma unroll
            for (int r = 0; r < 4; r++) a0[r] += EXP2(s[r] + lgl[h]);
            f32x4 s2 = __builtin_amdgcn_mfma_f32_16x16x32_bf16(kb2, qh, (f32x4){0.f,0.f,0.f,0.f}, 0, 0, 0);
            #pragma unroll
            for (int r = 0; r < 4; r++) a1[r] += EXP2(s2[r] + lgl[h]);
        }
        float* sp = &attn_score[(size_t)(b*MQ + m0 + l15) * NSC + kbase + g*4];
        *(f32x4*)sp = a0;
        *(f32x4*)(sp + 16) = a1;
    }
}

extern "C" void kernel_launch(void* const* d_in, const int* in_sizes, int n_in,
                              void* d_out, int out_size, void* d_ws, size_t ws_size,
                              hipStream_t stream)
{
    const float* hidden = (const float*)d_in[0];
    const float* scene  = (const float*)d_in[1];
    const float* in_w   = (const float*)d_in[2];
    const float* in_b   = (const float*)d_in[3];
    const float* out_w  = (const float*)d_in[4];
    const float* out_b  = (const float*)d_in[5];
    const float* aln_g  = (const float*)d_in[6];
    const float* aln_b  = (const float*)d_in[7];
    const float* ff1_w  = (const float*)d_in[8];
    const float* ff1_b  = (const float*)d_in[9];
    const float* ff2_w  = (const float*)d_in[10];
    const float* ff2_b  = (const float*)d_in[11];
    const float* fln_g  = (const float*)d_in[12];
    const float* fln_b  = (const float*)d_in[13];

    float* out0  = (float*)d_out;
    float* score = out0 + (size_t)BATCH * MQ * H;

    ushort* qb   = (ushort*)d_ws;                    // 16384x256 bf16
    ushort* kb   = qb   + 4194304;                   // 2048x256 bf16
    ushort* vtb  = kb   + 524288;                    // [b][256][512] bf16
    ushort* ctxb = vtb  + 524288;                    // 16384x256 bf16
    ushort* xbh  = ctxb + 4194304;                   // 16384x256 bf16
    ushort* fb   = xbh  + 4194304;                   // 16384x128 bf16
    ushort* wq   = fb   + 2097152;                   // 768x256 bf16
    ushort* wo   = wq   + 196608;                    // 256x256 bf16
    ushort* w1   = wo   + 65536;                     // 128x256 bf16
    ushort* w2   = w1   + 32768;                     // 256x128 bf16
    float*  xb   = (float*)(w2 + 32768);             // 16384x256 f32

    // (1/sqrt(32)) * log2(e): q pre-scaled so attn uses exp2 directly
    const float alpha_q = 0.25507609683638066f;
    dim3 blk(512);

    Cvt4 ca;
    ca.s[0]=in_w;  ca.d[0]=wq; ca.n[0]=196608;
    ca.s[1]=out_w; ca.d[1]=wo; ca.n[1]=65536;
    ca.s[2]=ff1_w; ca.d[2]=w1; ca.n[2]=32768;
    ca.s[3]=ff2_w; ca.d[3]=w2; ca.n[3]=32768;
    cvt_kernel<<<dim3(96, 4), dim3(256), 0, stream>>>(ca);

    // q = bf16((hidden @ Wq^T + bq) * alpha_q)
    gemm_kernel<0,0,256><<<dim3(1,512), blk, 0, stream>>>(
        hidden, wq, in_b, nullptr, nullptr, nullptr, qb, nullptr, 256, 256, alpha_q, 0);
    // k (bf16 row-major) + vT (bf16 transposed) in one GEMM
    gemm_kernel<0,1,256><<<dim3(2,64), blk, 0, stream>>>(
        scene, wq + 65536, in_b + 256, nullptr, nullptr, nullptr, kb, vtb, 256, 512, 1.f, 0);
    // fused MFMA attention -> ctx bf16 + attn_score f32
    attn_kernel<<<dim3(1024), blk, 0, stream>>>(qb, kb, vtb, ctxb, score);
    // x = LN(ctx @ Wout^T + bout + hidden): f32 xb + bf16 xbh
    gemm_kernel<1,2,256><<<dim3(1,512), blk, 0, stream>>>(
        ctxb, wo, out_b, hidden, aln_g, aln_b, xb, xbh, 256, 256, 1.f, 0);
    // f = bf16(relu(x @ W1^T + b1))
    gemm_kernel<1,0,128><<<dim3(1,512), blk, 0, stream>>>(
        xbh, w1, ff1_b, nullptr, nullptr, nullptr, fb, nullptr, 256, 128, 1.f, 1);
    // out = LN(f @ W2^T + b2 + x)
    gemm_kernel<1,2,256><<<dim3(1,512), blk, 0, stream>>>(
        fb, w2, ff2_b, xb, fln_g, fln_b, out0, nullptr, 128, 256, 1.f, 0);
}

// Round 7
// 207.476 us; speedup vs baseline: 1.7114x; 1.7114x over previous
//
#include <hip/hip_runtime.h>
#include <hip/hip_bf16.h>

#define H 256
#define NSC 512
#define MQ 4096
#define BATCH 4

typedef __attribute__((ext_vector_type(8))) short bf16x8;
typedef __attribute__((ext_vector_type(4))) float f32x4;

__device__ __forceinline__ ushort f2bf(float x) {
    union { float f; unsigned u; } c; c.f = x;
    unsigned r = c.u + 0x7FFF + ((c.u >> 16) & 1);   // RNE
    return (ushort)(r >> 16);
}
// pack bf16(hi),bf16(lo) -> one dword (truncation, 1 v_perm)
__device__ __forceinline__ unsigned pk2(float hi, float lo) {
    union { float f; unsigned u; } a, b; a.f = hi; b.f = lo;
    return __builtin_amdgcn_perm(a.u, b.u, 0x07060302u);
}
__device__ __forceinline__ uint4 cvt8f(const float* p) {
    float4 a = *(const float4*)p;
    float4 b = *(const float4*)(p + 4);
    uint4 r;
    r.x = pk2(a.y, a.x); r.y = pk2(a.w, a.z);
    r.z = pk2(b.y, b.x); r.w = pk2(b.w, b.z);
    return r;
}
#define EXP2(x) __builtin_amdgcn_exp2f(x)

// ---- bf16 MFMA GEMM, block = 64 rows x 256 cols, 512 thr = 8 waves (2x4).
// A: f32 (ATYPE 0, inline cvt) or bf16 (ATYPE 1); W always f32, cvt in staging.
// MODE 0: D = bf16(act((A@W^T + bias)*alpha)), stride N, cols guarded by N.
// MODE 1: kv split: col<256 -> bf16 k[row*256+col]; col>=256 -> vT
//         out2[((row>>9)*256 + col-256)*512 + (row&511)].
// MODE 2: fused add+LN: v = A@W^T + bias + res; LN over the 256-col row;
//         f32 out [row*256+col], optional bf16 out2.
template<int ATYPE, int MODE>
__global__ __launch_bounds__(512, 4) void gemm_kernel(
    const void* __restrict__ Ain, const float* __restrict__ W,
    const float* __restrict__ bias, const float* __restrict__ res,
    const float* __restrict__ lng, const float* __restrict__ lnb,
    void* __restrict__ out, ushort* __restrict__ out2,
    int K, int N, float alpha, int relu)
{
    __shared__ ushort As[64 * 64];
    __shared__ ushort Bs[256 * 64];
    __shared__ float Ls[64 * 4];
    __shared__ float Lq[64 * 4];
    const int t = threadIdx.x;
    const int w = t >> 6, lane = t & 63, g = lane >> 4, l15 = lane & 15;
    const int rowBase = blockIdx.y * 64;
    const int colBase = blockIdx.x * 256;
    const int wr = (w >> 2) * 32;
    const int wc = (w & 3) * 64;
    f32x4 acc[2][4];
    #pragma unroll
    for (int mt = 0; mt < 2; mt++)
        #pragma unroll
        for (int nt = 0; nt < 4; nt++) acc[mt][nt] = (f32x4){0.f,0.f,0.f,0.f};

    const int sr = t >> 3, skc = t & 7, sp = skc ^ (sr & 7);

    for (int k0 = 0; k0 < K; k0 += 64) {
        uint4 av;
        if (ATYPE == 0) {
            av = cvt8f((const float*)Ain + (size_t)(rowBase + sr) * K + k0 + skc*8);
        } else {
            av = *(const uint4*)((const ushort*)Ain + (size_t)(rowBase + sr) * K + k0 + skc*8);
        }
        uint4 bv[4];
        #pragma unroll
        for (int i = 0; i < 4; i++) {
            const int u = t + 512*i, br = u >> 3, bkc = u & 7;
            int brow = colBase + br; if (brow > N - 1) brow = N - 1;
            bv[i] = cvt8f(W + (size_t)brow * K + k0 + bkc*8);
        }
        __syncthreads();
        *(uint4*)&As[sr*64 + sp*8] = av;
        #pragma unroll
        for (int i = 0; i < 4; i++) {
            const int u = t + 512*i, br = u >> 3, bkc = u & 7, bp = bkc ^ (br & 7);
            *(uint4*)&Bs[br*64 + bp*8] = bv[i];
        }
        __syncthreads();
        #pragma unroll
        for (int kk = 0; kk < 2; kk++) {
            const int swz = ((kk*4 + g) ^ (l15 & 7)) * 8;
            bf16x8 af[2], bfr[4];
            #pragma unroll
            for (int mt = 0; mt < 2; mt++)
                af[mt] = *(const bf16x8*)&As[(wr + mt*16 + l15)*64 + swz];
            #pragma unroll
            for (int nt = 0; nt < 4; nt++)
                bfr[nt] = *(const bf16x8*)&Bs[(wc + nt*16 + l15)*64 + swz];
            #pragma unroll
            for (int mt = 0; mt < 2; mt++)
                #pragma unroll
                for (int nt = 0; nt < 4; nt++)
                    acc[mt][nt] = __builtin_amdgcn_mfma_f32_16x16x32_bf16(
                        af[mt], bfr[nt], acc[mt][nt], 0, 0, 0);
        }
    }

    if (MODE == 0) {
        #pragma unroll
        for (int nt = 0; nt < 4; nt++) {
            const int col = colBase + wc + nt*16 + l15;
            if (col < N) {
                const float bb = bias[col];
                #pragma unroll
                for (int mt = 0; mt < 2; mt++)
                    #pragma unroll
                    for (int r = 0; r < 4; r++) {
                        const int row = rowBase + wr + mt*16 + g*4 + r;
                        float o = (acc[mt][nt][r] + bb) * alpha;
                        if (relu) o = fmaxf(o, 0.f);
                        ((ushort*)out)[(size_t)row * N + col] = f2bf(o);
                    }
            }
        }
    } else if (MODE == 1) {
        #pragma unroll
        for (int nt = 0; nt < 4; nt++) {
            const int col = colBase + wc + nt*16 + l15;
            const float bb = bias[col];
            #pragma unroll
            for (int mt = 0; mt < 2; mt++) {
                const int row0 = rowBase + wr + mt*16 + g*4;
                if (col < 256) {
                    #pragma unroll
                    for (int r = 0; r < 4; r++)
                        ((ushort*)out)[(size_t)(row0 + r) * 256 + col] = f2bf(acc[mt][nt][r] + bb);
                } else {
                    ushort4 pkv = { f2bf(acc[mt][nt][0] + bb), f2bf(acc[mt][nt][1] + bb),
                                    f2bf(acc[mt][nt][2] + bb), f2bf(acc[mt][nt][3] + bb) };
                    *(ushort4*)&out2[(size_t)((row0 >> 9)*256 + col - 256) * 512 + (row0 & 511)] = pkv;
                }
            }
        }
    } else {
        float bb[4], gmv[4], btv[4];
        #pragma unroll
        for (int nt = 0; nt < 4; nt++) {
            const int col = wc + nt*16 + l15;
            bb[nt] = bias[col]; gmv[nt] = lng[col]; btv[nt] = lnb[col];
        }
        #pragma unroll
        for (int mt = 0; mt < 2; mt++)
            #pragma unroll
            for (int r = 0; r < 4; r++) {
                const int row = rowBase + wr + mt*16 + g*4 + r;
                const float* rp = res + (size_t)row * 256;
                #pragma unroll
                for (int nt = 0; nt < 4; nt++)
                    acc[mt][nt][r] += bb[nt] + rp[wc + nt*16 + l15];
            }
        float ps[2][4], pq[2][4];
        #pragma unroll
        for (int mt = 0; mt < 2; mt++)
            #pragma unroll
            for (int r = 0; r < 4; r++) {
                float s = (acc[mt][0][r] + acc[mt][1][r]) + (acc[mt][2][r] + acc[mt][3][r]);
                float qq = (acc[mt][0][r]*acc[mt][0][r] + acc[mt][1][r]*acc[mt][1][r])
                         + (acc[mt][2][r]*acc[mt][2][r] + acc[mt][3][r]*acc[mt][3][r]);
                #pragma unroll
                for (int m = 1; m < 16; m <<= 1) {
                    s += __shfl_xor(s, m);
                    qq += __shfl_xor(qq, m);
                }
                ps[mt][r] = s; pq[mt][r] = qq;
            }
        if (l15 == 0) {
            #pragma unroll
            for (int mt = 0; mt < 2; mt++)
                #pragma unroll
                for (int r = 0; r < 4; r++) {
                    const int ri = wr + mt*16 + g*4 + r;
                    Ls[ri*4 + (w & 3)] = ps[mt][r];
                    Lq[ri*4 + (w & 3)] = pq[mt][r];
                }
        }
        __syncthreads();
        #pragma unroll
        for (int mt = 0; mt < 2; mt++)
            #pragma unroll
            for (int r = 0; r < 4; r++) {
                const int ri = wr + mt*16 + g*4 + r;
                const int row = rowBase + ri;
                f32x4 sv = *(const f32x4*)&Ls[ri*4];
                f32x4 qv = *(const f32x4*)&Lq[ri*4];
                const float mu = (sv[0]+sv[1]+sv[2]+sv[3]) * (1.f/256.f);
                const float ex2 = (qv[0]+qv[1]+qv[2]+qv[3]) * (1.f/256.f);
                const float rs = rsqrtf(ex2 - mu*mu + 1e-6f);
                #pragma unroll
                for (int nt = 0; nt < 4; nt++) {
                    const int col = wc + nt*16 + l15;
                    const float o = (acc[mt][nt][r] - mu) * rs * gmv[nt] + btv[nt];
                    ((float*)out)[(size_t)row * 256 + col] = o;
                    if (out2) out2[(size_t)row * 256 + col] = f2bf(o);
                }
            }
    }
}

// ---- Flash MFMA cross-attention. Block = 512 thr = 8 waves, 32 queries,
// grid 512 (2 blocks/CU). q pre-scaled by log2(e)/sqrt(d) -> p = exp2(s).
// Pass 1 (R2 structure, best measured): wave = head; K,V staged coalesced in
// LDS; P C->A transpose via per-wave stride-40 LDS roundtrip.
// Pass 2 (register): wave w owns keys [64w,64w+64); computes S^T for all 8
// heads via mfma(A=K,B=Q), head-mean with exp2(s + lgl[h]) in registers,
// coalesced f32x4 score writes. One barrier between passes.
__global__ __launch_bounds__(512, 4) void attn_kernel(
    const ushort* __restrict__ q, const ushort* __restrict__ k,
    const ushort* __restrict__ vt, ushort* __restrict__ ctx_out,
    float* __restrict__ attn_score)
{
    __shared__ ushort Ks[32 * 264];      // [key][256 d + 8 pad]
    __shared__ ushort Vs[256 * 40];      // [d][32 keys + 8 pad]
    __shared__ ushort Pb[8 * 32 * 40];   // per-wave [32 q][32 keys + 8 pad]
    __shared__ float Lg[256];            // lgl per (head, q)
    const int t = threadIdx.x;
    const int w = t >> 6;                // head (pass 1) / key-chunk (pass 2)
    const int lane = t & 63;
    const int g = lane >> 4;
    const int l15 = lane & 15;
    const int b = blockIdx.x >> 7;
    const int m0 = (blockIdx.x & 127) * 32;

    const size_t kg = (size_t)b * NSC * H;
    const size_t vg = (size_t)b * H * NSC;

    // Q A-fragments: lane holds Q[m=l15][k=8g..8g+7] per 16-q tile
    bf16x8 qf[2];
    #pragma unroll
    for (int qt = 0; qt < 2; qt++)
        qf[qt] = *(const bf16x8*)&q[((size_t)(b*MQ + m0 + qt*16 + l15)) * H + w*32 + g*8];

    f32x4 cacc[2][2];
    float lacc[2][4];
    #pragma unroll
    for (int qt = 0; qt < 2; qt++) {
        #pragma unroll
        for (int dt = 0; dt < 2; dt++) cacc[qt][dt] = (f32x4){0.f,0.f,0.f,0.f};
        #pragma unroll
        for (int r = 0; r < 4; r++) lacc[qt][r] = 0.f;
    }

    // ---- pass 1: denominators + ctx ----
    for (int c = 0; c < 16; c++) {
        const int kbase = c * 32;
        __syncthreads();
        #pragma unroll
        for (int i = 0; i < 2; i++) {
            int u = t + 512 * i;
            int key = u >> 5, part = u & 31;
            *(bf16x8*)&Ks[key*264 + part*8] =
                *(const bf16x8*)&k[kg + (size_t)(kbase + key)*H + part*8];
            int d = u >> 2, p2 = u & 3;
            *(bf16x8*)&Vs[d*40 + p2*8] =
                *(const bf16x8*)&vt[vg + (size_t)d*NSC + kbase + p2*8];
        }
        __syncthreads();
        #pragma unroll
        for (int qt = 0; qt < 2; qt++) {
            #pragma unroll
            for (int kt = 0; kt < 2; kt++) {
                bf16x8 kf = *(const bf16x8*)&Ks[(kt*16 + l15)*264 + w*32 + g*8];
                f32x4 s = __builtin_amdgcn_mfma_f32_16x16x32_bf16(
                    qf[qt], kf, (f32x4){0.f,0.f,0.f,0.f}, 0, 0, 0);
                #pragma unroll
                for (int r = 0; r < 4; r++) {
                    float p = EXP2(s[r]);
                    lacc[qt][r] += p;
                    Pb[(w*32 + qt*16 + g*4 + r)*40 + kt*16 + l15] = f2bf(p);
                }
            }
        }
        #pragma unroll
        for (int qt = 0; qt < 2; qt++) {
            bf16x8 pf = *(const bf16x8*)&Pb[(w*32 + qt*16 + l15)*40 + g*8];
            #pragma unroll
            for (int dt = 0; dt < 2; dt++) {
                bf16x8 vf = *(const bf16x8*)&Vs[(w*32 + dt*16 + l15)*40 + g*8];
                cacc[qt][dt] = __builtin_amdgcn_mfma_f32_16x16x32_bf16(
                    pf, vf, cacc[qt][dt], 0, 0, 0);
            }
        }
    }

    // reduce l over key-cols (lanes sharing g), write ctx + Lg
    #pragma unroll
    for (int qt = 0; qt < 2; qt++) {
        float invl[4];
        #pragma unroll
        for (int r = 0; r < 4; r++) {
            float v = lacc[qt][r];
            v += __shfl_xor(v, 1); v += __shfl_xor(v, 2);
            v += __shfl_xor(v, 4); v += __shfl_xor(v, 8);
            invl[r] = 1.f / v;
            if (l15 == 0) Lg[w*32 + qt*16 + g*4 + r] = -__log2f(v) - 3.0f;
        }
        #pragma unroll
        for (int dt = 0; dt < 2; dt++)
            #pragma unroll
            for (int r = 0; r < 4; r++)
                ctx_out[((size_t)(b*MQ + m0 + qt*16 + g*4 + r))*H + w*32 + dt*16 + l15]
                    = f2bf(cacc[qt][dt][r] * invl[r]);
    }

    __syncthreads();

    // ---- pass 2: attn_score = mean over heads; wave w -> keys [64w, 64w+64)
    f32x4 sacc[2][4];
    #pragma unroll
    for (int qt = 0; qt < 2; qt++)
        #pragma unroll
        for (int kt = 0; kt < 4; kt++) sacc[qt][kt] = (f32x4){0.f,0.f,0.f,0.f};

    #pragma unroll 2
    for (int h = 0; h < 8; h++) {
        const float lg0 = Lg[h*32 + l15];
        const float lg1 = Lg[h*32 + 16 + l15];
        bf16x8 q0 = *(const bf16x8*)&q[((size_t)(b*MQ + m0 + l15)) * H + h*32 + g*8];
        bf16x8 q1 = *(const bf16x8*)&q[((size_t)(b*MQ + m0 + 16 + l15)) * H + h*32 + g*8];
        #pragma unroll
        for (int kt = 0; kt < 4; kt++) {
            bf16x8 kf = *(const bf16x8*)&k[kg + (size_t)(w*64 + kt*16 + l15)*H + h*32 + g*8];
            f32x4 s0 = __builtin_amdgcn_mfma_f32_16x16x32_bf16(
                kf, q0, (f32x4){0.f,0.f,0.f,0.f}, 0, 0, 0);
            #pragma unroll
            for (int r = 0; r < 4; r++) sacc[0][kt][r] += EXP2(s0[r] + lg0);
            f32x4 s1 = __builtin_amdgcn_mfma_f32_16x16x32_bf16(
                kf, q1, (f32x4){0.f,0.f,0.f,0.f}, 0, 0, 0);
            #pragma unroll
            for (int r = 0; r < 4; r++) sacc[1][kt][r] += EXP2(s1[r] + lg1);
        }
    }
    #pragma unroll
    for (int qt = 0; qt < 2; qt++)
        #pragma unroll
        for (int kt = 0; kt < 4; kt++)
            *(f32x4*)&attn_score[((size_t)(b*MQ + m0 + qt*16 + l15))*NSC + w*64 + kt*16 + g*4]
                = sacc[qt][kt];
}

extern "C" void kernel_launch(void* const* d_in, const int* in_sizes, int n_in,
                              void* d_out, int out_size, void* d_ws, size_t ws_size,
                              hipStream_t stream)
{
    const float* hidden = (const float*)d_in[0];
    const float* scene  = (const float*)d_in[1];
    const float* in_w   = (const float*)d_in[2];
    const float* in_b   = (const float*)d_in[3];
    const float* out_w  = (const float*)d_in[4];
    const float* out_b  = (const float*)d_in[5];
    const float* aln_g  = (const float*)d_in[6];
    const float* aln_b  = (const float*)d_in[7];
    const float* ff1_w  = (const float*)d_in[8];
    const float* ff1_b  = (const float*)d_in[9];
    const float* ff2_w  = (const float*)d_in[10];
    const float* ff2_b  = (const float*)d_in[11];
    const float* fln_g  = (const float*)d_in[12];
    const float* fln_b  = (const float*)d_in[13];

    float* out0  = (float*)d_out;
    float* score = out0 + (size_t)BATCH * MQ * H;

    ushort* qb   = (ushort*)d_ws;                    // 16384x256 bf16
    ushort* kb   = qb   + 4194304;                   // 2048x256 bf16
    ushort* vtb  = kb   + 524288;                    // [b][256][512] bf16
    ushort* ctxb = vtb  + 524288;                    // 16384x256 bf16
    ushort* xbh  = ctxb + 4194304;                   // 16384x256 bf16
    ushort* fb   = xbh  + 4194304;                   // 16384x128 bf16
    float*  xb   = (float*)(fb + 2097152);           // 16384x256 f32

    // (1/sqrt(32)) * log2(e): q pre-scaled so attn uses exp2 directly
    const float alpha_q = 0.25507609683638066f;
    dim3 blk(512);

    // q = bf16((hidden @ Wq^T + bq) * alpha_q)
    gemm_kernel<0,0><<<dim3(1,256), blk, 0, stream>>>(
        hidden, in_w, in_b, nullptr, nullptr, nullptr, qb, nullptr, 256, 256, alpha_q, 0);
    // k (bf16 row-major) + vT (bf16 transposed) in one GEMM
    gemm_kernel<0,1><<<dim3(2,32), blk, 0, stream>>>(
        scene, in_w + 65536, in_b + 256, nullptr, nullptr, nullptr, kb, vtb, 256, 512, 1.f, 0);
    // fused MFMA attention -> ctx bf16 + attn_score f32
    attn_kernel<<<dim3(512), blk, 0, stream>>>(qb, kb, vtb, ctxb, score);
    // x = LN(ctx @ Wout^T + bout + hidden): f32 xb + bf16 xbh
    gemm_kernel<1,2><<<dim3(1,256), blk, 0, stream>>>(
        ctxb, out_w, out_b, hidden, aln_g, aln_b, xb, xbh, 256, 256, 1.f, 0);
    // f = bf16(relu(x @ W1^T + b1))
    gemm_kernel<1,0><<<dim3(1,256), blk, 0, stream>>>(
        xbh, ff1_w, ff1_b, nullptr, nullptr, nullptr, fb, nullptr, 256, 128, 1.f, 1);
    // out = LN(f @ W2^T + b2 + x)
    gemm_kernel<1,2><<<dim3(1,256), blk, 0, stream>>>(
        fb, ff2_w, ff2_b, xb, fln_g, fln_b, out0, nullptr, 128, 256, 1.f, 0);
}